// Round 11
// baseline (47.312 us; speedup 1.0000x reference)
//
#include <hip/hip_runtime.h>
#include <math.h>
#include <stdint.h>

#define DIM 4194304
#define RBLOCKS 1024
#define RTHREADS 256
#define FBLOCKS 2048
#define FTHREADS 256
#define EPSF 1e-24f
#define SCALE 256.0f

// d_ws dword layout
#define WS_PART 0     // 2048: per-block partial sums
#define WS_W21 2048   // 128 dwords: layer-A A-frag lower K-half (per-lane 2 dwords)
#define WS_W3 2176
#define WS_W4 2304
#define WS_W5 2432
#define WS_W67 2560   // 16 f32 (w67 padded)

typedef uint32_t u32;
typedef __fp16 fp16x2 __attribute__((ext_vector_type(2)));
typedef __fp16 half8 __attribute__((ext_vector_type(8)));
typedef float f32x4 __attribute__((ext_vector_type(4)));
typedef uint32_t u32x2 __attribute__((ext_vector_type(2)));
typedef uint32_t u32x4 __attribute__((ext_vector_type(4)));

__device__ __forceinline__ u32 pack2u(float a, float b) {
    fp16x2 r = __builtin_amdgcn_cvt_pkrtz(a, b);
    return __builtin_bit_cast(u32, r);
}

// gfx950-native MFMA (HW-verified shape): D = A(16x32) * B(32x16) + C
__device__ __forceinline__ f32x4 mfma32(half8 a, half8 b, f32x4 c) {
    return __builtin_amdgcn_mfma_f32_16x16x32_f16(a, b, c, 0, 0, 0);
}
// relu(f32x4) -> lower-K-half B-fragment: cvt_pkrtz x2 then packed max x2 (4 VALU)
__device__ __forceinline__ half8 relucvt8(f32x4 a) {
    fp16x2 z2 = {(__fp16)0.f, (__fp16)0.f};
    fp16x2 c0 = __builtin_amdgcn_cvt_pkrtz(a[0], a[1]);
    fp16x2 c1 = __builtin_amdgcn_cvt_pkrtz(a[2], a[3]);
    c0 = __builtin_elementwise_max(c0, z2);
    c1 = __builtin_elementwise_max(c1, z2);
    u32x4 r = {__builtin_bit_cast(u32, c0), __builtin_bit_cast(u32, c1), 0u, 0u};
    return __builtin_bit_cast(half8, r);
}

// ------- Kernel 1: block-partial norms; block 0 also packs MFMA weight fragments -------
__global__ __launch_bounds__(RTHREADS) void k_reduce(
    const float* __restrict__ grad, const float* __restrict__ xp, const float* __restrict__ xc,
    const float* __restrict__ Wc1, const float* __restrict__ Wc2, const float* __restrict__ Wc3,
    const float* __restrict__ Wc4, const float* __restrict__ Wc5, const float* __restrict__ Wc6,
    const float* __restrict__ Wc7, float* __restrict__ ws) {
    if (blockIdx.x == 0) {
        u32* wsu = (u32*)ws;
        int t = threadIdx.x;
        if (t < 128) {
            // dword t = lane*2 + d holds W[m][k0], W[m][k0+1]; m=lane&15, g=lane>>4, k0=4g+2d
            int lane = t >> 1, d = t & 1;
            int m = lane & 15, gg = lane >> 4;
            int k0 = 4 * gg + 2 * d;
            float a0 = 0.f, a1 = 0.f;
            if (m < 10 && k0 < 3) {
                for (int j = 0; j < 10; ++j) a0 += Wc2[m * 10 + j] * Wc1[j * 3 + k0];
                if (k0 == 2) a0 *= (1.f / SCALE);
            }
            if (m < 10 && k0 + 1 < 3) {
                for (int j = 0; j < 10; ++j) a1 += Wc2[m * 10 + j] * Wc1[j * 3 + k0 + 1];
                if (k0 + 1 == 2) a1 *= (1.f / SCALE);
            }
            wsu[WS_W21 + t] = pack2u(a0, a1);
            float v0, v1;
            v0 = (m < 10 && k0 < 10) ? Wc3[m * 10 + k0] : 0.f;
            v1 = (m < 10 && k0 + 1 < 10) ? Wc3[m * 10 + k0 + 1] : 0.f;
            wsu[WS_W3 + t] = pack2u(v0, v1);
            v0 = (m < 10 && k0 < 10) ? Wc4[m * 10 + k0] : 0.f;
            v1 = (m < 10 && k0 + 1 < 10) ? Wc4[m * 10 + k0 + 1] : 0.f;
            wsu[WS_W4 + t] = pack2u(v0, v1);
            v0 = (m < 10 && k0 < 10) ? Wc5[m * 10 + k0] : 0.f;
            v1 = (m < 10 && k0 + 1 < 10) ? Wc5[m * 10 + k0 + 1] : 0.f;
            wsu[WS_W5 + t] = pack2u(v0, v1);
        }
        if (t >= 128 && t < 144) {
            int j = t - 128;
            float w = 0.f;
            if (j < 10)
                for (int k = 0; k < 10; ++k) w += Wc7[k] * Wc6[k * 10 + j];
            ws[WS_W67 + j] = w;
        }
    }
    const float4* g4 = reinterpret_cast<const float4*>(grad);
    const float4* p4 = reinterpret_cast<const float4*>(xp);
    const float4* c4 = reinterpret_cast<const float4*>(xc);
    int tid = blockIdx.x * RTHREADS + threadIdx.x;
    float sg = 0.f, sm = 0.f;
    constexpr int STRIDE = RBLOCKS * RTHREADS;
#pragma unroll
    for (int it = 0; it < (DIM / 4) / STRIDE; ++it) {  // 4 iters
        int i = tid + it * STRIDE;
        float4 gv = g4[i];
        float4 pv = p4[i];
        float4 cv = c4[i];
        sg += gv.x * gv.x + gv.y * gv.y + gv.z * gv.z + gv.w * gv.w;
        float mx = cv.x - pv.x, my = cv.y - pv.y, mz = cv.z - pv.z, mw = cv.w - pv.w;
        sm += mx * mx + my * my + mz * mz + mw * mw;
    }
#pragma unroll
    for (int off = 32; off > 0; off >>= 1) {
        sg += __shfl_down(sg, off);
        sm += __shfl_down(sm, off);
    }
    __shared__ float wg[4], wm[4];
    int wave = threadIdx.x >> 6;
    if ((threadIdx.x & 63) == 0) {
        wg[wave] = sg;
        wm[wave] = sm;
    }
    __syncthreads();
    if (threadIdx.x == 0) {
        ws[WS_PART + 2 * blockIdx.x]     = wg[0] + wg[1] + wg[2] + wg[3];
        ws[WS_PART + 2 * blockIdx.x + 1] = wm[0] + wm[1] + wm[2] + wm[3];
    }
}

// ------- Kernel 2: redundant scalar finish + register-resident MFMA network -------
__global__ __launch_bounds__(FTHREADS, 4) void k_fused(
    const float* __restrict__ grad, const float* __restrict__ xp, const float* __restrict__ xc,
    const float* __restrict__ loss_curr, const float* __restrict__ loss_prev,
    const float* __restrict__ Wl1, const float* __restrict__ Wl2, const float* __restrict__ Wl3,
    const float* __restrict__ Wl4, const float* __restrict__ Wl5,
    const float* __restrict__ ws, float* __restrict__ out) {
    __shared__ float sc[3];
    __shared__ float red[8];
    const int tid = threadIdx.x;
    const int lane = tid & 63;

    // ---- issue ALL global loads up front: 2 float4 per array per lane (512 elems/wave) ----
    const float4* g4 = reinterpret_cast<const float4*>(grad);
    const float4* p4 = reinterpret_cast<const float4*>(xp);
    const float4* c4 = reinterpret_cast<const float4*>(xc);
    const int wave_gid = blockIdx.x * (FTHREADS / 64) + (tid >> 6);
    const int wb = wave_gid * 128;  // float4 base for this wave
    float4 gA = g4[wb + lane], gB = g4[wb + 64 + lane];
    float4 pA = p4[wb + lane], pB = p4[wb + 64 + lane];
    float4 cA = c4[wb + lane], cB = c4[wb + 64 + lane];

    // ---- phase A: every block finishes the norms in fixed order (identical result) ----
    {
        float fg = 0.f, fm = 0.f;
        for (int i = tid; i < RBLOCKS; i += FTHREADS) {
            fg += ws[WS_PART + 2 * i];
            fm += ws[WS_PART + 2 * i + 1];
        }
#pragma unroll
        for (int off = 32; off > 0; off >>= 1) {
            fg += __shfl_down(fg, off);
            fm += __shfl_down(fm, off);
        }
        int wv = tid >> 6;
        if ((tid & 63) == 0) {
            red[wv] = fg;
            red[4 + wv] = fm;
        }
        __syncthreads();
        if (tid == 0) {
            float g2 = red[0] + red[1] + red[2] + red[3];
            float m2 = red[4] + red[5] + red[6] + red[7];
            float g_norm = sqrtf(g2), m_norm = sqrtf(m2);
            float g_inv = (g_norm > EPSF) ? 1.f / g_norm : 1.f;
            float m_inv = (m_norm > EPSF) ? 1.f / m_norm : 1.f;
            float feats[4] = {log1pf(g_norm), log1pf(m_norm), log1pf(loss_curr[0]),
                              log1pf(loss_prev[0])};
            float h1[8], h2_[8], h3[8], h4[8];
#pragma unroll
            for (int o = 0; o < 8; ++o) {
                float acc = 0.f;
                for (int i = 0; i < 4; ++i) acc += Wl1[o * 4 + i] * feats[i];
                h1[o] = fmaxf(acc, 0.f);
            }
#pragma unroll
            for (int o = 0; o < 8; ++o) {
                float acc = 0.f;
                for (int i = 0; i < 8; ++i) acc += Wl2[o * 8 + i] * h1[i];
                h2_[o] = fmaxf(acc, 0.f);
            }
#pragma unroll
            for (int o = 0; o < 8; ++o) {
                float acc = 0.f;
                for (int i = 0; i < 8; ++i) acc += Wl3[o * 8 + i] * h2_[i];
                h3[o] = fmaxf(acc, 0.f);
            }
#pragma unroll
            for (int o = 0; o < 8; ++o) {
                float acc = 0.f;
                for (int i = 0; i < 8; ++i) acc += Wl4[o * 8 + i] * h3[i];
                h4[o] = acc;  // no relu
            }
            float step = 0.f;
            for (int i = 0; i < 8; ++i) step += Wl5[i] * h4[i];
            sc[0] = g_inv * SCALE;
            sc[1] = m_inv * SCALE;
            sc[2] = step * (1.f / SCALE);
        }
        __syncthreads();
    }
    const float gs = sc[0], ms = sc[1], step_eff = sc[2];

    // ---- per-lane weight fragments: lower K-half from ws, upper K-half = 0 ----
    const u32* wsu = (const u32*)ws;
    const int n = lane & 15, g = lane >> 4;
#define LOADFRAG(NAME, OFS)                                                    \
    half8 NAME;                                                                \
    {                                                                          \
        u32x2 lo = ((const u32x2*)(wsu + (OFS)))[lane];                        \
        u32x4 fr = {lo[0], lo[1], 0u, 0u};                                     \
        NAME = __builtin_bit_cast(half8, fr);                                  \
    }
    LOADFRAG(w21f, WS_W21)
    LOADFRAG(w3f, WS_W3)
    LOADFRAG(w4f, WS_W4)
    LOADFRAG(w5f, WS_W5)
#undef LOADFRAG
    half8 w67f;
    {
        const float* w67p = ws + WS_W67;  // w67 replicated into all 16 A-rows
        u32x4 fr = {pack2u(w67p[4 * g], w67p[4 * g + 1]),
                    pack2u(w67p[4 * g + 2], w67p[4 * g + 3]), 0u, 0u};
        w67f = __builtin_bit_cast(half8, fr);
    }
    const f32x4 zf = {0.f, 0.f, 0.f, 0.f};

    // ---- pack all 8 elements' inputs into registers (pk index = pass index) ----
    u32 pk0s[8], pk1s[8];
    {
        float Ga[4] = {gA.x * gs, gA.y * gs, gA.z * gs, gA.w * gs};
        float Ma[4] = {(cA.x - pA.x) * ms, (cA.y - pA.y) * ms, (cA.z - pA.z) * ms,
                       (cA.w - pA.w) * ms};
        float Gb[4] = {gB.x * gs, gB.y * gs, gB.z * gs, gB.w * gs};
        float Mb[4] = {(cB.x - pB.x) * ms, (cB.y - pB.y) * ms, (cB.z - pB.z) * ms,
                       (cB.w - pB.w) * ms};
#pragma unroll
        for (int s = 0; s < 4; ++s) {
            pk0s[s] = pack2u(Ga[s], Ma[s]);
            pk1s[s] = pack2u(Ga[s] * Ma[s], 0.f);
            pk0s[4 + s] = pack2u(Gb[s], Mb[s]);
            pk1s[4 + s] = pack2u(Gb[s] * Mb[s], 0.f);
        }
    }

    // ---- 8 register-resident passes; pass j handles elements {4*l'+ (j&3)} of chunk j>>2 ----
    float dres[8];
#pragma unroll
    for (int j = 0; j < 8; ++j) {
        u32 b0[4], b1[4];
#pragma unroll
        for (int t = 0; t < 4; ++t) {
            int idx = (n + 16 * t) << 2;
            b0[t] = (u32)__builtin_amdgcn_ds_bpermute(idx, (int)pk0s[j]);
            b1[t] = (u32)__builtin_amdgcn_ds_bpermute(idx, (int)pk1s[j]);
        }
        f32x4 acc[4];
#pragma unroll
        for (int t = 0; t < 4; ++t) {
            u32x4 bb = {b0[t], b1[t], 0u, 0u};
            acc[t] = mfma32(w21f, __builtin_bit_cast(half8, bb), zf);
        }
#pragma unroll
        for (int t = 0; t < 4; ++t) acc[t] = mfma32(w3f, relucvt8(acc[t]), zf);
#pragma unroll
        for (int t = 0; t < 4; ++t) acc[t] = mfma32(w4f, relucvt8(acc[t]), zf);
#pragma unroll
        for (int t = 0; t < 4; ++t) acc[t] = mfma32(w5f, relucvt8(acc[t]), zf);
#pragma unroll
        for (int t = 0; t < 4; ++t) acc[t] = mfma32(w67f, relucvt8(acc[t]), zf);
        dres[j] = (g == 0) ? acc[0][0] : (g == 1) ? acc[1][0] : (g == 2) ? acc[2][0]
                                                                         : acc[3][0];
    }

    // ---- epilogue: lane's own 8 elements = (chunk A, s=0..3), (chunk B, s=0..3) ----
    float4* o4 = reinterpret_cast<float4*>(out);
    float4 ovA, ovB;
    ovA.x = fmaf(-step_eff, dres[0], cA.x);
    ovA.y = fmaf(-step_eff, dres[1], cA.y);
    ovA.z = fmaf(-step_eff, dres[2], cA.z);
    ovA.w = fmaf(-step_eff, dres[3], cA.w);
    ovB.x = fmaf(-step_eff, dres[4], cB.x);
    ovB.y = fmaf(-step_eff, dres[5], cB.y);
    ovB.z = fmaf(-step_eff, dres[6], cB.z);
    ovB.w = fmaf(-step_eff, dres[7], cB.w);
    o4[wb + lane] = ovA;
    o4[wb + 64 + lane] = ovB;
}

extern "C" void kernel_launch(void* const* d_in, const int* in_sizes, int n_in,
                              void* d_out, int out_size, void* d_ws, size_t ws_size,
                              hipStream_t stream) {
    const float* grad      = (const float*)d_in[0];
    const float* xp        = (const float*)d_in[1];
    const float* xc        = (const float*)d_in[2];
    const float* loss_curr = (const float*)d_in[3];
    const float* loss_prev = (const float*)d_in[4];
    const float* Wc1 = (const float*)d_in[5];
    const float* Wc2 = (const float*)d_in[6];
    const float* Wc3 = (const float*)d_in[7];
    const float* Wc4 = (const float*)d_in[8];
    const float* Wc5 = (const float*)d_in[9];
    const float* Wc6 = (const float*)d_in[10];
    const float* Wc7 = (const float*)d_in[11];
    const float* Wl1 = (const float*)d_in[12];
    const float* Wl2 = (const float*)d_in[13];
    const float* Wl3 = (const float*)d_in[14];
    const float* Wl4 = (const float*)d_in[15];
    const float* Wl5 = (const float*)d_in[16];

    float* ws  = (float*)d_ws;
    float* out = (float*)d_out;

    k_reduce<<<RBLOCKS, RTHREADS, 0, stream>>>(grad, xp, xc, Wc1, Wc2, Wc3, Wc4, Wc5, Wc6,
                                               Wc7, ws);
    k_fused<<<FBLOCKS, FTHREADS, 0, stream>>>(grad, xp, xc, loss_curr, loss_prev, Wl1, Wl2,
                                              Wl3, Wl4, Wl5, ws, out);
}

// Round 12
// 38.875 us; speedup vs baseline: 1.2170x; 1.2170x over previous
//
#include <hip/hip_runtime.h>
#include <math.h>
#include <stdint.h>

#define DIM 4194304
#define RBLOCKS 1024
#define RTHREADS 256
#define FBLOCKS 2048
#define FTHREADS 256
#define TOTTH (FBLOCKS * FTHREADS)  // 524288
#define PASSES (DIM / TOTTH)        // 8
#define EPSF 1e-24f
#define SCALE 256.0f

// d_ws dword layout
#define WS_PART 0     // 2048: per-block partial sums
#define WS_W21 2048   // 128 dwords: layer-A A-frag lower K-half (per-lane 2 dwords)
#define WS_W3 2176
#define WS_W4 2304
#define WS_W5 2432
#define WS_W67 2560   // 16 f32 (w67 padded)

typedef uint32_t u32;
typedef __fp16 fp16x2 __attribute__((ext_vector_type(2)));
typedef __fp16 half8 __attribute__((ext_vector_type(8)));
typedef float f32x4 __attribute__((ext_vector_type(4)));
typedef uint32_t u32x2 __attribute__((ext_vector_type(2)));
typedef uint32_t u32x4 __attribute__((ext_vector_type(4)));

__device__ __forceinline__ u32 pack2u(float a, float b) {
    fp16x2 r = __builtin_amdgcn_cvt_pkrtz(a, b);
    return __builtin_bit_cast(u32, r);
}

// gfx950-native MFMA (HW-verified shape): D = A(16x32) * B(32x16) + C
__device__ __forceinline__ f32x4 mfma32(half8 a, half8 b, f32x4 c) {
    return __builtin_amdgcn_mfma_f32_16x16x32_f16(a, b, c, 0, 0, 0);
}
// relu(f32x4) -> lower-K-half B-fragment: cvt_pkrtz x2 then packed max x2 (4 VALU)
__device__ __forceinline__ half8 relucvt8(f32x4 a) {
    fp16x2 z2 = {(__fp16)0.f, (__fp16)0.f};
    fp16x2 c0 = __builtin_amdgcn_cvt_pkrtz(a[0], a[1]);
    fp16x2 c1 = __builtin_amdgcn_cvt_pkrtz(a[2], a[3]);
    c0 = __builtin_elementwise_max(c0, z2);
    c1 = __builtin_elementwise_max(c1, z2);
    u32x4 r = {__builtin_bit_cast(u32, c0), __builtin_bit_cast(u32, c1), 0u, 0u};
    return __builtin_bit_cast(half8, r);
}

// ------- Kernel 1: block-partial norms; block 0 also packs MFMA weight fragments -------
__global__ __launch_bounds__(RTHREADS) void k_reduce(
    const float* __restrict__ grad, const float* __restrict__ xp, const float* __restrict__ xc,
    const float* __restrict__ Wc1, const float* __restrict__ Wc2, const float* __restrict__ Wc3,
    const float* __restrict__ Wc4, const float* __restrict__ Wc5, const float* __restrict__ Wc6,
    const float* __restrict__ Wc7, float* __restrict__ ws) {
    if (blockIdx.x == 0) {
        u32* wsu = (u32*)ws;
        int t = threadIdx.x;
        if (t < 128) {
            // dword t = lane*2 + d holds W[m][k0], W[m][k0+1]; m=lane&15, g=lane>>4, k0=4g+2d
            int lane = t >> 1, d = t & 1;
            int m = lane & 15, gg = lane >> 4;
            int k0 = 4 * gg + 2 * d;
            float a0 = 0.f, a1 = 0.f;
            if (m < 10 && k0 < 3) {
                for (int j = 0; j < 10; ++j) a0 += Wc2[m * 10 + j] * Wc1[j * 3 + k0];
                if (k0 == 2) a0 *= (1.f / SCALE);
            }
            if (m < 10 && k0 + 1 < 3) {
                for (int j = 0; j < 10; ++j) a1 += Wc2[m * 10 + j] * Wc1[j * 3 + k0 + 1];
                if (k0 + 1 == 2) a1 *= (1.f / SCALE);
            }
            wsu[WS_W21 + t] = pack2u(a0, a1);
            float v0, v1;
            v0 = (m < 10 && k0 < 10) ? Wc3[m * 10 + k0] : 0.f;
            v1 = (m < 10 && k0 + 1 < 10) ? Wc3[m * 10 + k0 + 1] : 0.f;
            wsu[WS_W3 + t] = pack2u(v0, v1);
            v0 = (m < 10 && k0 < 10) ? Wc4[m * 10 + k0] : 0.f;
            v1 = (m < 10 && k0 + 1 < 10) ? Wc4[m * 10 + k0 + 1] : 0.f;
            wsu[WS_W4 + t] = pack2u(v0, v1);
            v0 = (m < 10 && k0 < 10) ? Wc5[m * 10 + k0] : 0.f;
            v1 = (m < 10 && k0 + 1 < 10) ? Wc5[m * 10 + k0 + 1] : 0.f;
            wsu[WS_W5 + t] = pack2u(v0, v1);
        }
        if (t >= 128 && t < 144) {
            int j = t - 128;
            float w = 0.f;
            if (j < 10)
                for (int k = 0; k < 10; ++k) w += Wc7[k] * Wc6[k * 10 + j];
            ws[WS_W67 + j] = w;
        }
    }
    const float4* g4 = reinterpret_cast<const float4*>(grad);
    const float4* p4 = reinterpret_cast<const float4*>(xp);
    const float4* c4 = reinterpret_cast<const float4*>(xc);
    int tid = blockIdx.x * RTHREADS + threadIdx.x;
    float sg = 0.f, sm = 0.f;
    constexpr int STRIDE = RBLOCKS * RTHREADS;
#pragma unroll
    for (int it = 0; it < (DIM / 4) / STRIDE; ++it) {  // 4 iters
        int i = tid + it * STRIDE;
        float4 gv = g4[i];
        float4 pv = p4[i];
        float4 cv = c4[i];
        sg += gv.x * gv.x + gv.y * gv.y + gv.z * gv.z + gv.w * gv.w;
        float mx = cv.x - pv.x, my = cv.y - pv.y, mz = cv.z - pv.z, mw = cv.w - pv.w;
        sm += mx * mx + my * my + mz * mz + mw * mw;
    }
#pragma unroll
    for (int off = 32; off > 0; off >>= 1) {
        sg += __shfl_down(sg, off);
        sm += __shfl_down(sm, off);
    }
    __shared__ float wg[4], wm[4];
    int wave = threadIdx.x >> 6;
    if ((threadIdx.x & 63) == 0) {
        wg[wave] = sg;
        wm[wave] = sm;
    }
    __syncthreads();
    if (threadIdx.x == 0) {
        ws[WS_PART + 2 * blockIdx.x]     = wg[0] + wg[1] + wg[2] + wg[3];
        ws[WS_PART + 2 * blockIdx.x + 1] = wm[0] + wm[1] + wm[2] + wm[3];
    }
}

// ------- Kernel 2: redundant scalar finish + MFMA-chained direction network -------
__global__ __launch_bounds__(FTHREADS, 8) void k_fused(
    const float* __restrict__ grad, const float* __restrict__ xp, const float* __restrict__ xc,
    const float* __restrict__ loss_curr, const float* __restrict__ loss_prev,
    const float* __restrict__ Wl1, const float* __restrict__ Wl2, const float* __restrict__ Wl3,
    const float* __restrict__ Wl4, const float* __restrict__ Wl5,
    const float* __restrict__ ws, float* __restrict__ out) {
    __shared__ float sc[3];
    __shared__ float red[8];
    const int tid = threadIdx.x;
    const int lane = tid & 63;

    // ---- phase A: every block finishes the norms in fixed order (identical result) ----
    {
        float fg = 0.f, fm = 0.f;
        for (int i = tid; i < RBLOCKS; i += FTHREADS) {
            fg += ws[WS_PART + 2 * i];
            fm += ws[WS_PART + 2 * i + 1];
        }
#pragma unroll
        for (int off = 32; off > 0; off >>= 1) {
            fg += __shfl_down(fg, off);
            fm += __shfl_down(fm, off);
        }
        int wv = tid >> 6;
        if ((tid & 63) == 0) {
            red[wv] = fg;
            red[4 + wv] = fm;
        }
        __syncthreads();
        // lane-parallel scalar MLP on wave 0 (channels o = lane&7, redundant copies)
        if (tid < 64) {
            float g2 = red[0] + red[1] + red[2] + red[3];
            float m2 = red[4] + red[5] + red[6] + red[7];
            float g_norm = sqrtf(g2), m_norm = sqrtf(m2);
            float g_inv = (g_norm > EPSF) ? 1.f / g_norm : 1.f;
            float m_inv = (m_norm > EPSF) ? 1.f / m_norm : 1.f;
            float f0 = log1pf(g_norm), f1 = log1pf(m_norm);
            float f2 = log1pf(loss_curr[0]), f3 = log1pf(loss_prev[0]);
            int o = tid & 7;
            float h = fmaxf(Wl1[o * 4] * f0 + Wl1[o * 4 + 1] * f1 + Wl1[o * 4 + 2] * f2 +
                                Wl1[o * 4 + 3] * f3,
                            0.f);
            float acc = 0.f;
#pragma unroll
            for (int i = 0; i < 8; ++i) acc += Wl2[o * 8 + i] * __shfl(h, i);
            h = fmaxf(acc, 0.f);
            acc = 0.f;
#pragma unroll
            for (int i = 0; i < 8; ++i) acc += Wl3[o * 8 + i] * __shfl(h, i);
            h = fmaxf(acc, 0.f);
            acc = 0.f;
#pragma unroll
            for (int i = 0; i < 8; ++i) acc += Wl4[o * 8 + i] * __shfl(h, i);
            h = acc;  // no relu
            float step = 0.f;
#pragma unroll
            for (int i = 0; i < 8; ++i) step += Wl5[i] * __shfl(h, i);
            if (tid == 0) {
                sc[0] = g_inv * SCALE;
                sc[1] = m_inv * SCALE;
                sc[2] = step * (1.f / SCALE);
            }
        }
        __syncthreads();
    }
    const float gs = sc[0], ms = sc[1], step_eff = sc[2];

    // ---- per-lane weight fragments: lower K-half from ws, upper K-half = 0 ----
    const u32* wsu = (const u32*)ws;
    const int n = lane & 15, g = lane >> 4;
#define LOADFRAG(NAME, OFS)                                                    \
    half8 NAME;                                                                \
    {                                                                          \
        u32x2 lo = ((const u32x2*)(wsu + (OFS)))[lane];                        \
        u32x4 fr = {lo[0], lo[1], 0u, 0u};                                     \
        NAME = __builtin_bit_cast(half8, fr);                                  \
    }
    LOADFRAG(w21f, WS_W21)
    LOADFRAG(w3f, WS_W3)
    LOADFRAG(w4f, WS_W4)
    LOADFRAG(w5f, WS_W5)
#undef LOADFRAG
    half8 w67f;
    {
        const float* w67p = ws + WS_W67;  // w67 replicated into all 16 A-rows
        u32x4 fr = {pack2u(w67p[4 * g], w67p[4 * g + 1]),
                    pack2u(w67p[4 * g + 2], w67p[4 * g + 3]), 0u, 0u};
        w67f = __builtin_bit_cast(half8, fr);
    }
    const f32x4 zf = {0.f, 0.f, 0.f, 0.f};

    int ebase = (blockIdx.x * (FTHREADS / 64) + (tid >> 6)) * 64 + lane;
    int e = ebase;
    float gvv = grad[e], pvv = xp[e], cvv = xc[e];
#pragma unroll
    for (int p = 0; p < PASSES; ++p) {
        int en = (p + 1 < PASSES) ? (e + TOTTH) : 0;  // prefetch next pass (clamped)
        float gvn = grad[en], pvn = xp[en], cvn = xc[en];

        float Gf = gvv * gs;
        float Mf = (cvv - pvv) * ms;
        float GMf = Gf * Mf;
        u32 pk0 = pack2u(Gf, Mf), pk1 = pack2u(GMf, 0.f);

        // --- two steps of two tiles: low register footprint, static indexing ---
        float dhalf0, dhalf1;
#pragma unroll
        for (int st = 0; st < 2; ++st) {
            u32 b0[2], b1[2];
#pragma unroll
            for (int t = 0; t < 2; ++t) {
                int idx = (n + 16 * (2 * st + t)) << 2;
                b0[t] = (u32)__builtin_amdgcn_ds_bpermute(idx, (int)pk0);
                b1[t] = (u32)__builtin_amdgcn_ds_bpermute(idx, (int)pk1);
            }
            f32x4 acc[2];
#pragma unroll
            for (int t = 0; t < 2; ++t) {
                u32x4 bb = {b0[t], b1[t], 0u, 0u};
                acc[t] = mfma32(w21f, __builtin_bit_cast(half8, bb), zf);
            }
#pragma unroll
            for (int t = 0; t < 2; ++t) acc[t] = mfma32(w3f, relucvt8(acc[t]), zf);
#pragma unroll
            for (int t = 0; t < 2; ++t) acc[t] = mfma32(w4f, relucvt8(acc[t]), zf);
#pragma unroll
            for (int t = 0; t < 2; ++t) acc[t] = mfma32(w5f, relucvt8(acc[t]), zf);
#pragma unroll
            for (int t = 0; t < 2; ++t) acc[t] = mfma32(w67f, relucvt8(acc[t]), zf);
            float dsel = ((g & 1) == 0) ? acc[0][0] : acc[1][0];
            if (st == 0)
                dhalf0 = dsel;
            else
                dhalf1 = dsel;
        }
        float dsel = (g < 2) ? dhalf0 : dhalf1;
        out[e] = fmaf(-step_eff, dsel, cvv);

        e = (p + 1 < PASSES) ? en : e;
        gvv = gvn;
        pvv = pvn;
        cvv = cvn;
    }
}

extern "C" void kernel_launch(void* const* d_in, const int* in_sizes, int n_in,
                              void* d_out, int out_size, void* d_ws, size_t ws_size,
                              hipStream_t stream) {
    const float* grad      = (const float*)d_in[0];
    const float* xp        = (const float*)d_in[1];
    const float* xc        = (const float*)d_in[2];
    const float* loss_curr = (const float*)d_in[3];
    const float* loss_prev = (const float*)d_in[4];
    const float* Wc1 = (const float*)d_in[5];
    const float* Wc2 = (const float*)d_in[6];
    const float* Wc3 = (const float*)d_in[7];
    const float* Wc4 = (const float*)d_in[8];
    const float* Wc5 = (const float*)d_in[9];
    const float* Wc6 = (const float*)d_in[10];
    const float* Wc7 = (const float*)d_in[11];
    const float* Wl1 = (const float*)d_in[12];
    const float* Wl2 = (const float*)d_in[13];
    const float* Wl3 = (const float*)d_in[14];
    const float* Wl4 = (const float*)d_in[15];
    const float* Wl5 = (const float*)d_in[16];

    float* ws  = (float*)d_ws;
    float* out = (float*)d_out;

    k_reduce<<<RBLOCKS, RTHREADS, 0, stream>>>(grad, xp, xc, Wc1, Wc2, Wc3, Wc4, Wc5, Wc6,
                                               Wc7, ws);
    k_fused<<<FBLOCKS, FTHREADS, 0, stream>>>(grad, xp, xc, loss_curr, loss_prev, Wl1, Wl2,
                                              Wl3, Wl4, Wl5, ws, out);
}